// Round 1
// baseline (189.815 us; speedup 1.0000x reference)
//
#include <hip/hip_runtime.h>
#include <math.h>

#define BB 8
#define NN 4096
#define PP 16
#define SS 200

// ws layout (floats):
// [0, BB*PP*SS*4)       : X table as float4 {-2x,-2y,-2z, x^2+y^2+z^2}
// [X_END, X_END+2)      : accum[0]=cub_sum, accum[1]=cd_sum
// [X_END+2, X_END+130)  : colsum[B*P]
#define X_FLOATS (BB*PP*SS*4)

__global__ void sq_points_kernel(const float* __restrict__ scale,
                                 const float* __restrict__ shape_eps,
                                 const float* __restrict__ etas,
                                 const float* __restrict__ omegas,
                                 float4* __restrict__ X) {
    int idx = blockIdx.x * blockDim.x + threadIdx.x;   // (b*P + p)*S + s
    if (idx >= BB * PP * SS) return;
    int bp = idx / SS;
    float eta = etas[idx];
    float om  = omegas[idx];
    if (eta == 0.f) eta = 1e-6f;
    if (om  == 0.f) om  = 1e-6f;
    float a1 = scale[bp*3+0], a2 = scale[bp*3+1], a3 = scale[bp*3+2];
    float e1 = shape_eps[bp*2+0], e2 = shape_eps[bp*2+1];
    float ce = cosf(eta), se = sinf(eta);
    float co = cosf(om),  so = sinf(om);
    auto fexp = [](float x, float p) {
        float sg = (x > 0.f) ? 1.f : ((x < 0.f) ? -1.f : 0.f);
        return sg * powf(fabsf(x), p);
    };
    float fce = fexp(ce, e1);
    float x = a1 * fce * fexp(co, e2);
    float y = a2 * fce * fexp(so, e2);
    float z = a3 * fexp(se, e1);
    auto clampv = [](float v) {
        return ((v > 0.f) ? 1.f : -1.f) * fmaxf(fabsf(v), 1e-6f);
    };
    x = clampv(x); y = clampv(y); z = clampv(z);
    float xsq = x*x + y*y + z*z;
    X[idx] = make_float4(-2.f*x, -2.f*y, -2.f*z, xsq);
}

__global__ void colsum_kernel(const float* __restrict__ assign,
                              float* __restrict__ colsum) {
    int b = blockIdx.x;
    __shared__ float part[256][PP];
    float loc[PP];
#pragma unroll
    for (int p = 0; p < PP; p++) loc[p] = 0.f;
    for (int n = threadIdx.x; n < NN; n += 256) {
        const float4* row = (const float4*)(assign + ((size_t)b*NN + n) * PP);
#pragma unroll
        for (int q = 0; q < 4; q++) {
            float4 v = row[q];
            loc[q*4+0] += v.x; loc[q*4+1] += v.y;
            loc[q*4+2] += v.z; loc[q*4+3] += v.w;
        }
    }
#pragma unroll
    for (int p = 0; p < PP; p++) part[threadIdx.x][p] = loc[p];
    __syncthreads();
    if (threadIdx.x < PP) {
        float s = 0.f;
        for (int t = 0; t < 256; t++) s += part[t][threadIdx.x];
        colsum[b*PP + threadIdx.x] = s;
    }
}

__global__ __launch_bounds__(256) void main_kernel(
    const float* __restrict__ pc, const float* __restrict__ normals,
    const float* __restrict__ trans, const float* __restrict__ rotate,
    const float* __restrict__ scale, const float* __restrict__ assign,
    const float4* __restrict__ Xd, float* __restrict__ accum) {
    int blk = blockIdx.x;
    int b = blk >> 5;
    int rem = blk & 31;
    int phalf = rem >> 4;     // which half of the 16 primitives
    int chunk = rem & 15;     // which 256-chunk of N
    int n = chunk * 256 + threadIdx.x;

    __shared__ float4 Xs[8 * SS];          // 25.6 KB
    __shared__ float prim[8][16];          // trans[0:3], rot[3:12], scale[12:15]

    const float4* Xsrc = Xd + ((size_t)(b*PP + phalf*8)) * SS;
    for (int i = threadIdx.x; i < 8 * SS; i += 256) Xs[i] = Xsrc[i];
    if (threadIdx.x < 8 * 15) {
        int p = threadIdx.x / 15, k = threadIdx.x % 15;
        int pp = phalf*8 + p;
        float v;
        if (k < 3)        v = trans [(b*PP + pp)*3 + k];
        else if (k < 12)  v = rotate[(b*PP + pp)*9 + (k - 3)];
        else              v = scale [(b*PP + pp)*3 + (k - 12)];
        prim[p][k] = v;
    }
    __syncthreads();

    float px = pc[((size_t)b*NN + n)*3 + 0];
    float py = pc[((size_t)b*NN + n)*3 + 1];
    float pz = pc[((size_t)b*NN + n)*3 + 2];
    float qx = normals[((size_t)b*NN + n)*3 + 0];
    float qy = normals[((size_t)b*NN + n)*3 + 1];
    float qz = normals[((size_t)b*NN + n)*3 + 2];
    const float4* arow = (const float4*)(assign + ((size_t)b*NN + n)*PP + phalf*8);
    float4 a0 = arow[0], a1v = arow[1];
    float aw[8] = {a0.x, a0.y, a0.z, a0.w, a1v.x, a1v.y, a1v.z, a1v.w};

    float acc_cub = 0.f, acc_cd = 0.f;
#pragma unroll
    for (int p = 0; p < 8; p++) {
        float tx = prim[p][0], ty = prim[p][1], tz = prim[p][2];
        const float* R = &prim[p][3];
        float sx = prim[p][12], sy = prim[p][13], sz = prim[p][14];
        float d0 = px - tx, d1 = py - ty, d2 = pz - tz;
        float y0 = R[0]*d0 + R[3]*d1 + R[6]*d2;
        float y1 = R[1]*d0 + R[4]*d1 + R[7]*d2;
        float y2 = R[2]*d0 + R[5]*d1 + R[8]*d2;
        float e0 = qx - tx, e1 = qy - ty, e2 = qz - tz;
        float m0 = R[0]*e0 + R[3]*e1 + R[6]*e2;
        float m1 = R[1]*e0 + R[4]*e1 + R[7]*e2;
        float m2 = R[2]*e0 + R[5]*e1 + R[8]*e2;

        // ---- cuboid loss ----
        float nrm = fmaxf(sqrtf(m0*m0 + m1*m1 + m2*m2), 1e-4f);
        float sims[6] = {-m0/nrm, m0/nrm, -m1/nrm, m1/nrm, -m2/nrm, m2/nrm};
        int fidx = 0; float best = sims[0];
#pragma unroll
        for (int f = 1; f < 6; f++) if (sims[f] > best) { best = sims[f]; fidx = f; }
        int axis = fidx >> 1;
        float sgn = (fidx & 1) ? 1.f : -1.f;
        float pjx = fminf(fmaxf(y0, -sx), sx);
        float pjy = fminf(fmaxf(y1, -sy), sy);
        float pjz = fminf(fmaxf(y2, -sz), sz);
        if (axis == 0)      pjx = sgn * sx;
        else if (axis == 1) pjy = sgn * sy;
        else                pjz = sgn * sz;
        float dx = pjx - y0, dy = pjy - y1, dz = pjz - y2;
        float diff = dx*dx + dy*dy + dz*dz;

        // ---- chamfer to SQ samples ----
        float ysq = y0*y0 + y1*y1 + y2*y2;
        float mmin = 1e30f;
        const float4* Xp = &Xs[p * SS];
#pragma unroll 4
        for (int s = 0; s < SS; s++) {
            float4 xd = Xp[s];
            float dd = fmaf(xd.x, y0, fmaf(xd.y, y1, fmaf(xd.z, y2, xd.w)));
            mmin = fminf(mmin, dd);
        }
        float D = fmaxf(mmin + ysq, 0.f);

        acc_cub += diff * aw[p];
        acc_cd  += D    * aw[p];
    }

    // block reduction
#pragma unroll
    for (int off = 32; off > 0; off >>= 1) {
        acc_cub += __shfl_down(acc_cub, off, 64);
        acc_cd  += __shfl_down(acc_cd,  off, 64);
    }
    __shared__ float rc[4], rd[4];
    int wave = threadIdx.x >> 6, lane = threadIdx.x & 63;
    if (lane == 0) { rc[wave] = acc_cub; rd[wave] = acc_cd; }
    __syncthreads();
    if (threadIdx.x == 0) {
        atomicAdd(&accum[0], rc[0]+rc[1]+rc[2]+rc[3]);
        atomicAdd(&accum[1], rd[0]+rd[1]+rd[2]+rd[3]);
    }
}

__global__ void finalize_kernel(const float* __restrict__ exist,
                                const float* __restrict__ colsum,
                                const float* __restrict__ accum,
                                float* __restrict__ out) {
    int t = threadIdx.x;  // 0..127 -> b*16+p
    __shared__ float bce_s[128], sq_s[128];
    float cs = colsum[t];
    float gt = (cs > 24.0f) ? 1.f : 0.f;
    float pe = exist[t];
    float lg  = fmaxf(logf(pe), -100.f);
    float lg1 = fmaxf(logf(1.f - pe), -100.f);
    bce_s[t] = -(gt * lg + (1.f - gt) * lg1);
    sq_s[t] = sqrtf(cs / (float)NN + 0.01f);
    __syncthreads();
    if (t == 0) {
        float ext = 0.f;
        for (int i = 0; i < 128; i++) ext += bce_s[i];
        ext /= 128.f;
        float sps = 0.f;
        for (int b = 0; b < 8; b++) {
            float mb = 0.f;
            for (int p = 0; p < 16; p++) mb += sq_s[b*16 + p];
            mb /= 16.f;
            sps += mb * mb;
        }
        sps /= 8.f;
        float cub = accum[0] / (float)(BB * NN);
        float p2p = accum[1] / (float)(BB * NN);
        float cd  = 2.f * p2p;
        out[0] = 1.0f * cub + 1.0f * cd + 0.1f * ext + 0.1f * sps;
    }
}

extern "C" void kernel_launch(void* const* d_in, const int* in_sizes, int n_in,
                              void* d_out, int out_size, void* d_ws, size_t ws_size,
                              hipStream_t stream) {
    const float* pc        = (const float*)d_in[0];
    const float* normals   = (const float*)d_in[1];
    const float* trans     = (const float*)d_in[2];
    const float* rotate    = (const float*)d_in[3];
    const float* scale     = (const float*)d_in[4];
    const float* shape_eps = (const float*)d_in[5];
    const float* exist     = (const float*)d_in[6];
    const float* assign    = (const float*)d_in[7];
    const float* etas      = (const float*)d_in[8];
    const float* omegas    = (const float*)d_in[9];

    float* ws = (float*)d_ws;
    float4* X = (float4*)ws;
    float* accum  = ws + X_FLOATS;
    float* colsum = accum + 2;

    hipMemsetAsync(accum, 0, 2 * sizeof(float), stream);
    sq_points_kernel<<<(BB*PP*SS + 255)/256, 256, 0, stream>>>(scale, shape_eps, etas, omegas, X);
    colsum_kernel<<<BB, 256, 0, stream>>>(assign, colsum);
    main_kernel<<<BB*32, 256, 0, stream>>>(pc, normals, trans, rotate, scale, assign, X, accum);
    finalize_kernel<<<1, 128, 0, stream>>>(exist, colsum, accum, (float*)d_out);
}

// Round 2
// 121.419 us; speedup vs baseline: 1.5633x; 1.5633x over previous
//
#include <hip/hip_runtime.h>
#include <math.h>

#define BB 8
#define NN 4096
#define PP 16
#define SS 200

// ws layout (floats):
// [0, X_FLOATS)             : X table as float4 {-2x,-2y,-2z, x^2+y^2+z^2}
// [X_FLOATS, +2)            : accum[0]=cub_sum, accum[1]=cd_sum
// [X_FLOATS+2, +130)        : colsum[B*P]
#define X_FLOATS (BB*PP*SS*4)

__global__ void sq_points_kernel(const float* __restrict__ scale,
                                 const float* __restrict__ shape_eps,
                                 const float* __restrict__ etas,
                                 const float* __restrict__ omegas,
                                 float4* __restrict__ X) {
    int idx = blockIdx.x * blockDim.x + threadIdx.x;   // (b*P + p)*S + s
    if (idx >= BB * PP * SS) return;
    int bp = idx / SS;
    float eta = etas[idx];
    float om  = omegas[idx];
    if (eta == 0.f) eta = 1e-6f;
    if (om  == 0.f) om  = 1e-6f;
    float a1 = scale[bp*3+0], a2 = scale[bp*3+1], a3 = scale[bp*3+2];
    float e1 = shape_eps[bp*2+0], e2 = shape_eps[bp*2+1];
    float ce = cosf(eta), se = sinf(eta);
    float co = cosf(om),  so = sinf(om);
    auto fexp = [](float x, float p) {
        float sg = (x > 0.f) ? 1.f : ((x < 0.f) ? -1.f : 0.f);
        return sg * powf(fabsf(x), p);
    };
    float fce = fexp(ce, e1);
    float x = a1 * fce * fexp(co, e2);
    float y = a2 * fce * fexp(so, e2);
    float z = a3 * fexp(se, e1);
    auto clampv = [](float v) {
        return ((v > 0.f) ? 1.f : -1.f) * fmaxf(fabsf(v), 1e-6f);
    };
    x = clampv(x); y = clampv(y); z = clampv(z);
    float xsq = x*x + y*y + z*z;
    X[idx] = make_float4(-2.f*x, -2.f*y, -2.f*z, xsq);
}

// 64 blocks: b = blk>>3, n-chunk of 512. Atomic partial column sums.
__global__ void colsum_kernel(const float* __restrict__ assign,
                              float* __restrict__ colsum) {
    int b = blockIdx.x >> 3;
    int chunk = blockIdx.x & 7;
    __shared__ float part[256][PP];
    float loc[PP];
#pragma unroll
    for (int p = 0; p < PP; p++) loc[p] = 0.f;
#pragma unroll
    for (int j = 0; j < 2; j++) {
        int n = chunk * 512 + j * 256 + threadIdx.x;
        const float4* row = (const float4*)(assign + ((size_t)b*NN + n) * PP);
#pragma unroll
        for (int q = 0; q < 4; q++) {
            float4 v = row[q];
            loc[q*4+0] += v.x; loc[q*4+1] += v.y;
            loc[q*4+2] += v.z; loc[q*4+3] += v.w;
        }
    }
#pragma unroll
    for (int p = 0; p < PP; p++) part[threadIdx.x][p] = loc[p];
    __syncthreads();
    if (threadIdx.x < PP) {
        float s = 0.f;
        for (int t = 0; t < 256; t++) s += part[t][threadIdx.x];
        atomicAdd(&colsum[b*PP + threadIdx.x], s);
    }
}

// One (b, p) per block; 256 threads x 2 points each; samples via wave-uniform
// scalar loads (no LDS). 4 independent min-chains per point.
__global__ __launch_bounds__(256) void main_kernel(
    const float* __restrict__ pc, const float* __restrict__ normals,
    const float* __restrict__ trans, const float* __restrict__ rotate,
    const float* __restrict__ scale, const float* __restrict__ assign,
    const float4* __restrict__ Xd, float* __restrict__ accum) {
    int blk = blockIdx.x;
    int chunk = blk & 7;
    int p = (blk >> 3) & 15;
    int b = blk >> 7;
    int bp = b * PP + p;

    // wave-uniform primitive params -> scalar regs
    float tx = trans[bp*3+0], ty = trans[bp*3+1], tz = trans[bp*3+2];
    float R0 = rotate[bp*9+0], R1 = rotate[bp*9+1], R2 = rotate[bp*9+2];
    float R3 = rotate[bp*9+3], R4 = rotate[bp*9+4], R5 = rotate[bp*9+5];
    float R6 = rotate[bp*9+6], R7 = rotate[bp*9+7], R8 = rotate[bp*9+8];
    float sx = scale[bp*3+0], sy = scale[bp*3+1], sz = scale[bp*3+2];
    const float4* __restrict__ Xp = Xd + (size_t)bp * SS;

    float y0[2], y1[2], y2[2], aw[2], cubd[2], ysq[2];
#pragma unroll
    for (int j = 0; j < 2; j++) {
        int n = chunk * 512 + j * 256 + threadIdx.x;
        size_t base = ((size_t)b * NN + n) * 3;
        float px = pc[base+0], py = pc[base+1], pz = pc[base+2];
        float qx = normals[base+0], qy = normals[base+1], qz = normals[base+2];
        aw[j] = assign[((size_t)b * NN + n) * PP + p];

        float d0 = px - tx, d1 = py - ty, d2 = pz - tz;
        y0[j] = R0*d0 + R3*d1 + R6*d2;
        y1[j] = R1*d0 + R4*d1 + R7*d2;
        y2[j] = R2*d0 + R5*d1 + R8*d2;
        float e0 = qx - tx, e1 = qy - ty, e2 = qz - tz;
        float m0 = R0*e0 + R3*e1 + R6*e2;
        float m1 = R1*e0 + R4*e1 + R7*e2;
        float m2 = R2*e0 + R5*e1 + R8*e2;

        // ---- cuboid loss ----
        float rn = 1.f / fmaxf(sqrtf(m0*m0 + m1*m1 + m2*m2), 1e-4f);
        float s0 = -m0*rn, s1 = m0*rn, s2 = -m1*rn, s3 = m1*rn, s4 = -m2*rn, s5 = m2*rn;
        int fidx = 0; float best = s0;
        if (s1 > best) { best = s1; fidx = 1; }
        if (s2 > best) { best = s2; fidx = 2; }
        if (s3 > best) { best = s3; fidx = 3; }
        if (s4 > best) { best = s4; fidx = 4; }
        if (s5 > best) { best = s5; fidx = 5; }
        int axis = fidx >> 1;
        float sgn = (fidx & 1) ? 1.f : -1.f;
        float pjx = fminf(fmaxf(y0[j], -sx), sx);
        float pjy = fminf(fmaxf(y1[j], -sy), sy);
        float pjz = fminf(fmaxf(y2[j], -sz), sz);
        if (axis == 0)      pjx = sgn * sx;
        else if (axis == 1) pjy = sgn * sy;
        else                pjz = sgn * sz;
        float dx = pjx - y0[j], dy = pjy - y1[j], dz = pjz - y2[j];
        cubd[j] = dx*dx + dy*dy + dz*dz;
        ysq[j] = y0[j]*y0[j] + y1[j]*y1[j] + y2[j]*y2[j];
    }

    // ---- chamfer: 200 samples, scalar-loaded; 4 min-chains per point ----
    float mm0[4] = {1e30f,1e30f,1e30f,1e30f};
    float mm1[4] = {1e30f,1e30f,1e30f,1e30f};
#pragma unroll 2
    for (int s = 0; s < SS; s += 4) {
        float4 x0 = Xp[s+0], x1 = Xp[s+1], x2 = Xp[s+2], x3 = Xp[s+3];
        mm0[0] = fminf(mm0[0], fmaf(x0.x, y0[0], fmaf(x0.y, y1[0], fmaf(x0.z, y2[0], x0.w))));
        mm0[1] = fminf(mm0[1], fmaf(x1.x, y0[0], fmaf(x1.y, y1[0], fmaf(x1.z, y2[0], x1.w))));
        mm0[2] = fminf(mm0[2], fmaf(x2.x, y0[0], fmaf(x2.y, y1[0], fmaf(x2.z, y2[0], x2.w))));
        mm0[3] = fminf(mm0[3], fmaf(x3.x, y0[0], fmaf(x3.y, y1[0], fmaf(x3.z, y2[0], x3.w))));
        mm1[0] = fminf(mm1[0], fmaf(x0.x, y0[1], fmaf(x0.y, y1[1], fmaf(x0.z, y2[1], x0.w))));
        mm1[1] = fminf(mm1[1], fmaf(x1.x, y0[1], fmaf(x1.y, y1[1], fmaf(x1.z, y2[1], x1.w))));
        mm1[2] = fminf(mm1[2], fmaf(x2.x, y0[1], fmaf(x2.y, y1[1], fmaf(x2.z, y2[1], x2.w))));
        mm1[3] = fminf(mm1[3], fmaf(x3.x, y0[1], fmaf(x3.y, y1[1], fmaf(x3.z, y2[1], x3.w))));
    }
    float mn0 = fminf(fminf(mm0[0], mm0[1]), fminf(mm0[2], mm0[3]));
    float mn1 = fminf(fminf(mm1[0], mm1[1]), fminf(mm1[2], mm1[3]));
    float D0 = fmaxf(mn0 + ysq[0], 0.f);
    float D1 = fmaxf(mn1 + ysq[1], 0.f);

    float acc_cub = cubd[0]*aw[0] + cubd[1]*aw[1];
    float acc_cd  = D0*aw[0] + D1*aw[1];

    // block reduction
#pragma unroll
    for (int off = 32; off > 0; off >>= 1) {
        acc_cub += __shfl_down(acc_cub, off, 64);
        acc_cd  += __shfl_down(acc_cd,  off, 64);
    }
    __shared__ float rc[4], rd[4];
    int wave = threadIdx.x >> 6, lane = threadIdx.x & 63;
    if (lane == 0) { rc[wave] = acc_cub; rd[wave] = acc_cd; }
    __syncthreads();
    if (threadIdx.x == 0) {
        atomicAdd(&accum[0], rc[0]+rc[1]+rc[2]+rc[3]);
        atomicAdd(&accum[1], rd[0]+rd[1]+rd[2]+rd[3]);
    }
}

__global__ void finalize_kernel(const float* __restrict__ exist,
                                const float* __restrict__ colsum,
                                const float* __restrict__ accum,
                                float* __restrict__ out) {
    int t = threadIdx.x;  // 0..127 -> b*16+p
    __shared__ float bce_s[128], sq_s[128];
    float cs = colsum[t];
    float gt = (cs > 24.0f) ? 1.f : 0.f;
    float pe = exist[t];
    float lg  = fmaxf(logf(pe), -100.f);
    float lg1 = fmaxf(logf(1.f - pe), -100.f);
    bce_s[t] = -(gt * lg + (1.f - gt) * lg1);
    sq_s[t] = sqrtf(cs / (float)NN + 0.01f);
    __syncthreads();
    if (t == 0) {
        float ext = 0.f;
        for (int i = 0; i < 128; i++) ext += bce_s[i];
        ext /= 128.f;
        float sps = 0.f;
        for (int b = 0; b < 8; b++) {
            float mb = 0.f;
            for (int p = 0; p < 16; p++) mb += sq_s[b*16 + p];
            mb /= 16.f;
            sps += mb * mb;
        }
        sps /= 8.f;
        float cub = accum[0] / (float)(BB * NN);
        float p2p = accum[1] / (float)(BB * NN);
        float cd  = 2.f * p2p;
        out[0] = 1.0f * cub + 1.0f * cd + 0.1f * ext + 0.1f * sps;
    }
}

extern "C" void kernel_launch(void* const* d_in, const int* in_sizes, int n_in,
                              void* d_out, int out_size, void* d_ws, size_t ws_size,
                              hipStream_t stream) {
    const float* pc        = (const float*)d_in[0];
    const float* normals   = (const float*)d_in[1];
    const float* trans     = (const float*)d_in[2];
    const float* rotate    = (const float*)d_in[3];
    const float* scale     = (const float*)d_in[4];
    const float* shape_eps = (const float*)d_in[5];
    const float* exist     = (const float*)d_in[6];
    const float* assign    = (const float*)d_in[7];
    const float* etas      = (const float*)d_in[8];
    const float* omegas    = (const float*)d_in[9];

    float* ws = (float*)d_ws;
    float4* X = (float4*)ws;
    float* accum  = ws + X_FLOATS;
    float* colsum = accum + 2;

    hipMemsetAsync(accum, 0, (2 + BB*PP) * sizeof(float), stream);
    sq_points_kernel<<<(BB*PP*SS + 255)/256, 256, 0, stream>>>(scale, shape_eps, etas, omegas, X);
    colsum_kernel<<<BB*8, 256, 0, stream>>>(assign, colsum);
    main_kernel<<<BB*PP*8, 256, 0, stream>>>(pc, normals, trans, rotate, scale, assign, X, accum);
    finalize_kernel<<<1, 128, 0, stream>>>(exist, colsum, accum, (float*)d_out);
}

// Round 3
// 116.609 us; speedup vs baseline: 1.6278x; 1.0413x over previous
//
#include <hip/hip_runtime.h>
#include <math.h>

#define BB 8
#define NN 4096
#define PP 16
#define SS 200

// ws layout (floats):
// [0, X_FLOATS)             : X table as float4 {-2x,-2y,-2z, x^2+y^2+z^2}
// [X_FLOATS, +2)            : accum[0]=cub_sum, accum[1]=cd_sum
// [X_FLOATS+2, +130)        : colsum[B*P]
#define X_FLOATS (BB*PP*SS*4)

__global__ void sq_points_kernel(const float* __restrict__ scale,
                                 const float* __restrict__ shape_eps,
                                 const float* __restrict__ etas,
                                 const float* __restrict__ omegas,
                                 float4* __restrict__ X,
                                 float* __restrict__ zero_region) {
    int idx = blockIdx.x * blockDim.x + threadIdx.x;   // (b*P + p)*S + s
    // zero accum[2] + colsum[128] (runs before main_kernel in stream order)
    if (blockIdx.x == 0 && threadIdx.x < 2 + BB*PP) zero_region[threadIdx.x] = 0.f;
    if (idx >= BB * PP * SS) return;
    int bp = idx / SS;
    float eta = etas[idx];
    float om  = omegas[idx];
    if (eta == 0.f) eta = 1e-6f;
    if (om  == 0.f) om  = 1e-6f;
    float a1 = scale[bp*3+0], a2 = scale[bp*3+1], a3 = scale[bp*3+2];
    float e1 = shape_eps[bp*2+0], e2 = shape_eps[bp*2+1];
    float ce = cosf(eta), se = sinf(eta);
    float co = cosf(om),  so = sinf(om);
    auto fexp = [](float x, float p) {
        float sg = (x > 0.f) ? 1.f : ((x < 0.f) ? -1.f : 0.f);
        return sg * powf(fabsf(x), p);
    };
    float fce = fexp(ce, e1);
    float x = a1 * fce * fexp(co, e2);
    float y = a2 * fce * fexp(so, e2);
    float z = a3 * fexp(se, e1);
    auto clampv = [](float v) {
        return ((v > 0.f) ? 1.f : -1.f) * fmaxf(fabsf(v), 1e-6f);
    };
    x = clampv(x); y = clampv(y); z = clampv(z);
    float xsq = x*x + y*y + z*z;
    X[idx] = make_float4(-2.f*x, -2.f*y, -2.f*z, xsq);
}

// One (b, p, n-chunk of 512) per block; 256 threads x 2 points.
// Sample table via wave-uniform scalar loads, software-pipelined one
// 8-sample group ahead. colsum (assign column sum) fused in.
__global__ __launch_bounds__(256) void main_kernel(
    const float* __restrict__ pc, const float* __restrict__ normals,
    const float* __restrict__ trans, const float* __restrict__ rotate,
    const float* __restrict__ scale, const float* __restrict__ assign,
    const float4* __restrict__ Xd, float* __restrict__ accum,
    float* __restrict__ colsum) {
    int blk = blockIdx.x;
    int chunk = blk & 7;
    int p = (blk >> 3) & 15;
    int b = blk >> 7;
    int bp = b * PP + p;

    // wave-uniform primitive params -> scalar regs
    float tx = trans[bp*3+0], ty = trans[bp*3+1], tz = trans[bp*3+2];
    float R0 = rotate[bp*9+0], R1 = rotate[bp*9+1], R2 = rotate[bp*9+2];
    float R3 = rotate[bp*9+3], R4 = rotate[bp*9+4], R5 = rotate[bp*9+5];
    float R6 = rotate[bp*9+6], R7 = rotate[bp*9+7], R8 = rotate[bp*9+8];
    float sx = scale[bp*3+0], sy = scale[bp*3+1], sz = scale[bp*3+2];
    const float4* __restrict__ Xp = Xd + (size_t)bp * SS;

    float y0[2], y1[2], y2[2], aw[2], cubd[2], ysq[2];
#pragma unroll
    for (int j = 0; j < 2; j++) {
        int n = chunk * 512 + j * 256 + threadIdx.x;
        size_t base = ((size_t)b * NN + n) * 3;
        float px = pc[base+0], py = pc[base+1], pz = pc[base+2];
        float qx = normals[base+0], qy = normals[base+1], qz = normals[base+2];
        aw[j] = assign[((size_t)b * NN + n) * PP + p];

        float d0 = px - tx, d1 = py - ty, d2 = pz - tz;
        y0[j] = R0*d0 + R3*d1 + R6*d2;
        y1[j] = R1*d0 + R4*d1 + R7*d2;
        y2[j] = R2*d0 + R5*d1 + R8*d2;
        float e0 = qx - tx, e1 = qy - ty, e2 = qz - tz;
        float m0 = R0*e0 + R3*e1 + R6*e2;
        float m1 = R1*e0 + R4*e1 + R7*e2;
        float m2 = R2*e0 + R5*e1 + R8*e2;

        // ---- cuboid loss ----
        float rn = 1.f / fmaxf(sqrtf(m0*m0 + m1*m1 + m2*m2), 1e-4f);
        float s0 = -m0*rn, s1 = m0*rn, s2 = -m1*rn, s3 = m1*rn, s4 = -m2*rn, s5 = m2*rn;
        int fidx = 0; float best = s0;
        if (s1 > best) { best = s1; fidx = 1; }
        if (s2 > best) { best = s2; fidx = 2; }
        if (s3 > best) { best = s3; fidx = 3; }
        if (s4 > best) { best = s4; fidx = 4; }
        if (s5 > best) { best = s5; fidx = 5; }
        int axis = fidx >> 1;
        float sgn = (fidx & 1) ? 1.f : -1.f;
        float pjx = fminf(fmaxf(y0[j], -sx), sx);
        float pjy = fminf(fmaxf(y1[j], -sy), sy);
        float pjz = fminf(fmaxf(y2[j], -sz), sz);
        if (axis == 0)      pjx = sgn * sx;
        else if (axis == 1) pjy = sgn * sy;
        else                pjz = sgn * sz;
        float dx = pjx - y0[j], dy = pjy - y1[j], dz = pjz - y2[j];
        cubd[j] = dx*dx + dy*dy + dz*dz;
        ysq[j] = y0[j]*y0[j] + y1[j]*y1[j] + y2[j]*y2[j];
    }

    // ---- chamfer: 200 samples, scalar loads pipelined one group ahead ----
    float mm0[4] = {1e30f,1e30f,1e30f,1e30f};
    float mm1[4] = {1e30f,1e30f,1e30f,1e30f};
    float4 cur[8], nxt[8];
#pragma unroll
    for (int k = 0; k < 8; k++) cur[k] = Xp[k];
#pragma unroll 1
    for (int s = 0; s < SS; s += 8) {
        int sn = s + 8;
        if (sn >= SS) sn = 0;          // last iter: dummy (unused) prefetch
#pragma unroll
        for (int k = 0; k < 8; k++) nxt[k] = Xp[sn + k];
#pragma unroll
        for (int k = 0; k < 8; k++) {
            float4 x = cur[k];
            int c = k & 3;
            mm0[c] = fminf(mm0[c], fmaf(x.x, y0[0], fmaf(x.y, y1[0], fmaf(x.z, y2[0], x.w))));
            mm1[c] = fminf(mm1[c], fmaf(x.x, y0[1], fmaf(x.y, y1[1], fmaf(x.z, y2[1], x.w))));
        }
#pragma unroll
        for (int k = 0; k < 8; k++) cur[k] = nxt[k];
    }
    float mn0 = fminf(fminf(mm0[0], mm0[1]), fminf(mm0[2], mm0[3]));
    float mn1 = fminf(fminf(mm1[0], mm1[1]), fminf(mm1[2], mm1[3]));
    float D0 = fmaxf(mn0 + ysq[0], 0.f);
    float D1 = fmaxf(mn1 + ysq[1], 0.f);

    float acc_cub = cubd[0]*aw[0] + cubd[1]*aw[1];
    float acc_cd  = D0*aw[0] + D1*aw[1];
    float acc_as  = aw[0] + aw[1];     // fused colsum partial

    // block reduction (3 values)
#pragma unroll
    for (int off = 32; off > 0; off >>= 1) {
        acc_cub += __shfl_down(acc_cub, off, 64);
        acc_cd  += __shfl_down(acc_cd,  off, 64);
        acc_as  += __shfl_down(acc_as,  off, 64);
    }
    __shared__ float rc[4], rd[4], ra[4];
    int wave = threadIdx.x >> 6, lane = threadIdx.x & 63;
    if (lane == 0) { rc[wave] = acc_cub; rd[wave] = acc_cd; ra[wave] = acc_as; }
    __syncthreads();
    if (threadIdx.x == 0) {
        atomicAdd(&accum[0], rc[0]+rc[1]+rc[2]+rc[3]);
        atomicAdd(&accum[1], rd[0]+rd[1]+rd[2]+rd[3]);
        atomicAdd(&colsum[bp], ra[0]+ra[1]+ra[2]+ra[3]);
    }
}

__global__ void finalize_kernel(const float* __restrict__ exist,
                                const float* __restrict__ colsum,
                                const float* __restrict__ accum,
                                float* __restrict__ out) {
    int t = threadIdx.x;  // 0..127 -> b*16+p
    __shared__ float bce_s[128], sq_s[128];
    float cs = colsum[t];
    float gt = (cs > 24.0f) ? 1.f : 0.f;
    float pe = exist[t];
    float lg  = fmaxf(logf(pe), -100.f);
    float lg1 = fmaxf(logf(1.f - pe), -100.f);
    bce_s[t] = -(gt * lg + (1.f - gt) * lg1);
    sq_s[t] = sqrtf(cs / (float)NN + 0.01f);
    __syncthreads();
    if (t == 0) {
        float ext = 0.f;
        for (int i = 0; i < 128; i++) ext += bce_s[i];
        ext /= 128.f;
        float sps = 0.f;
        for (int b = 0; b < 8; b++) {
            float mb = 0.f;
            for (int p = 0; p < 16; p++) mb += sq_s[b*16 + p];
            mb /= 16.f;
            sps += mb * mb;
        }
        sps /= 8.f;
        float cub = accum[0] / (float)(BB * NN);
        float p2p = accum[1] / (float)(BB * NN);
        float cd  = 2.f * p2p;
        out[0] = 1.0f * cub + 1.0f * cd + 0.1f * ext + 0.1f * sps;
    }
}

extern "C" void kernel_launch(void* const* d_in, const int* in_sizes, int n_in,
                              void* d_out, int out_size, void* d_ws, size_t ws_size,
                              hipStream_t stream) {
    const float* pc        = (const float*)d_in[0];
    const float* normals   = (const float*)d_in[1];
    const float* trans     = (const float*)d_in[2];
    const float* rotate    = (const float*)d_in[3];
    const float* scale     = (const float*)d_in[4];
    const float* shape_eps = (const float*)d_in[5];
    const float* exist     = (const float*)d_in[6];
    const float* assign    = (const float*)d_in[7];
    const float* etas      = (const float*)d_in[8];
    const float* omegas    = (const float*)d_in[9];

    float* ws = (float*)d_ws;
    float4* X = (float4*)ws;
    float* accum  = ws + X_FLOATS;
    float* colsum = accum + 2;

    sq_points_kernel<<<(BB*PP*SS + 255)/256, 256, 0, stream>>>(
        scale, shape_eps, etas, omegas, X, accum /* zeroes accum+colsum */);
    main_kernel<<<BB*PP*8, 256, 0, stream>>>(
        pc, normals, trans, rotate, scale, assign, X, accum, colsum);
    finalize_kernel<<<1, 128, 0, stream>>>(exist, colsum, accum, (float*)d_out);
}